// Round 12
// baseline (258.684 us; speedup 1.0000x reference)
//
#include <hip/hip_runtime.h>
#include <math.h>

typedef __attribute__((ext_vector_type(4))) int i32x4;

#define MFMA_I8(a, b, c) __builtin_amdgcn_mfma_i32_16x16x64_i8((a), (b), (c), 0, 0, 0)

__device__ __forceinline__ void gload16(const void* g, void* l) {
    __builtin_amdgcn_global_load_lds(
        (const __attribute__((address_space(1))) unsigned int*)g,
        (__attribute__((address_space(3))) unsigned int*)l, 16, 0, 0);
}

// ---------- prologue ----------
__global__ void init_slots(unsigned* slots) {
    if (threadIdx.x < 3) slots[threadIdx.x] = 0u;
}

// blockIdx.y: 0 -> W1, 1 -> W2, 2 -> x
__global__ void absmax3_kernel(const float* __restrict__ W1, const float* __restrict__ W2,
                               const float* __restrict__ x, int n4w, int n4x,
                               unsigned* __restrict__ slots) {
    const float* p = (blockIdx.y == 0) ? W1 : (blockIdx.y == 1) ? W2 : x;
    const int n4 = (blockIdx.y == 2) ? n4x : n4w;
    float m = 0.f;
    const float4* p4 = (const float4*)p;
    for (int i = blockIdx.x * blockDim.x + threadIdx.x; i < n4; i += gridDim.x * blockDim.x) {
        float4 v = p4[i];
        m = fmaxf(m, fmaxf(fmaxf(fabsf(v.x), fabsf(v.y)), fmaxf(fabsf(v.z), fabsf(v.w))));
    }
#pragma unroll
    for (int off = 32; off > 0; off >>= 1)
        m = fmaxf(m, __shfl_xor(m, off, 64));
    if ((threadIdx.x & 63) == 0) atomicMax(slots + blockIdx.y, __float_as_uint(m));
}

__device__ __forceinline__ int pack4(float a, float b, float c, float d) {
    return (int)(((unsigned)(unsigned char)(signed char)(int)a) |
                 (((unsigned)(unsigned char)(signed char)(int)b) << 8) |
                 (((unsigned)(unsigned char)(signed char)(int)c) << 16) |
                 (((unsigned)(unsigned char)(signed char)(int)d) << 24));
}

// blockIdx.y: 0 -> quant W1 -> i8, 1 -> quant W2 -> i8, 2 -> split x -> (q1|q2) i8
__global__ void prep_kernel(const float* __restrict__ W1, signed char* __restrict__ o1,
                            const float* __restrict__ W2, signed char* __restrict__ o2,
                            const float* __restrict__ x, signed char* __restrict__ xq,
                            int n4w, int n4x, const unsigned* __restrict__ slots) {
    if (blockIdx.y < 2) {
        const float* W = blockIdx.y ? W2 : W1;
        signed char* out = blockIdx.y ? o2 : o1;
        const float inv_s = 127.0f / __uint_as_float(slots[blockIdx.y]);
        const float4* W4 = (const float4*)W;
        for (int i = blockIdx.x * blockDim.x + threadIdx.x; i < n4w; i += gridDim.x * blockDim.x) {
            float4 v = W4[i];
            float q0 = fminf(fmaxf(rintf(v.x * inv_s), -127.f), 127.f);
            float q1 = fminf(fmaxf(rintf(v.y * inv_s), -127.f), 127.f);
            float q2 = fminf(fmaxf(rintf(v.z * inv_s), -127.f), 127.f);
            float q3 = fminf(fmaxf(rintf(v.w * inv_s), -127.f), 127.f);
            *(int*)(out + 4 * (size_t)i) = pack4(q0, q1, q2, q3);
        }
    } else {
        const float sx = __uint_as_float(slots[2]) / 127.0f;
        const float inv_sx = 1.0f / sx;
        const float r_scale = 255.0f * inv_sx;
        const float4* x4 = (const float4*)x;
        for (int i = blockIdx.x * blockDim.x + threadIdx.x; i < n4x; i += gridDim.x * blockDim.x) {
            int r = i / 192;  // 192 float4 per 768-row
            int c = (i - r * 192) * 4;
            float4 v = x4[i];
            float a0 = rintf(v.x * inv_sx), a1 = rintf(v.y * inv_sx);
            float a2 = rintf(v.z * inv_sx), a3 = rintf(v.w * inv_sx);
            float b0 = fminf(fmaxf(rintf((v.x - sx * a0) * r_scale), -127.f), 127.f);
            float b1 = fminf(fmaxf(rintf((v.y - sx * a1) * r_scale), -127.f), 127.f);
            float b2 = fminf(fmaxf(rintf((v.z - sx * a2) * r_scale), -127.f), 127.f);
            float b3 = fminf(fmaxf(rintf((v.w - sx * a3) * r_scale), -127.f), 127.f);
            size_t base = (size_t)r * 1536 + c;
            *(int*)(xq + base) = pack4(a0, a1, a2, a3);
            *(int*)(xq + base + 768) = pack4(b0, b1, b2, b3);
        }
    }
}

// ---------- 256x128 i8 GEMM (NT): acc = sum_k A[m,k]*B[n,(k mod bwrap)] ----------
// BK=64, 8 waves 4m x 2n (wave tile 64x64), packed 2-rows-per-128B-line granule-XOR
// swizzle (conflict-free, R10-verified). NEW (R12): TRIPLE-buffered DMA pipeline —
// tile t+3 staged at iter t, vmcnt(6) leaves 6 loads (2 tiles) in flight, giving
// ~2.3 tile-times of HBM-latency slack (R11 analysis: per-tile wall == one exposed
// HBM round trip; 2-deep gave only ~1.0 tile-time of slack).
// LDS: A 3x16KB @0, B 3x8KB @49152 -> 72KB/block, 2 blocks/CU.
template <int EPI>
__global__ __launch_bounds__(512, 4) void gemm_i8(
    const signed char* __restrict__ A, const signed char* __restrict__ B,
    const float* __restrict__ bias, const unsigned* __restrict__ slots,
    const float* __restrict__ sg_ptr, const float* __restrict__ so_ptr,
    signed char* __restrict__ out_b, float* __restrict__ out_f,
    int N, int lda, int ldb, int NT, int bwrap, int fold_t) {
    extern __shared__ char smem[];

    const int tid = threadIdx.x;
    const int lane = tid & 63;
    const int w = tid >> 6;
    const int wm = (w >> 1) * 64;  // 4m x 2n wave grid
    const int wn = (w & 1) * 64;
    const int lr16 = lane & 15;
    const int lkg = lane >> 4;

    // bijective XCD-aware swizzle (m204)
    const int gX = gridDim.x;
    const int nwg = gX * gridDim.y;
    const int orig = blockIdx.y * gX + blockIdx.x;
    const int qq = nwg >> 3, rr = nwg & 7;
    const int xcd = orig & 7, idx = orig >> 3;
    const int wg = (xcd < rr ? xcd * (qq + 1) : rr * (qq + 1) + (xcd - rr) * qq) + idx;
    const int m0 = (wg % gX) * 256;
    const int n0 = (wg / gX) * 128;

    // read-side: packed layout. global(row R, k-granule q) lives at
    // LDS line L=R>>1, phys granule p = ((R&1)*4+q) ^ (L&7). Here L&7 == lr16>>1.
    const int h8 = lr16 >> 1;
    const int pG = (((lr16 & 1) << 2) + lkg) ^ h8;
    const int rdA = wm * 64 + h8 * 128 + pG * 16;   // + f*1024 + buf*16384
    const int rdB = wn * 64 + h8 * 128 + pG * 16;   // + n*1024 (+49152 + buf*8192 via Bb)

    // stage-side: linear LDS dest (DMA), inverse-swizzled global source.
    const int Lw = lane >> 3;
    const int ll = (lane & 7) ^ Lw;
    const int dr = ll >> 2;
    const int dk = (ll & 3) << 4;
    const signed char* aSrc0 = A + (size_t)(m0 + w * 32 + 2 * Lw + dr) * lda + dk;
    const signed char* aSrc1 = A + (size_t)(m0 + w * 32 + 16 + 2 * Lw + dr) * lda + dk;
    const signed char* bSrc  = B + (size_t)(n0 + w * 16 + 2 * Lw + dr) * ldb + dk;

#define STAGE_A(P, KC)                                    \
    do {                                                  \
        char* _d = smem + (P) * 16384 + w * 2048;         \
        gload16(aSrc0 + (KC), _d);                        \
        gload16(aSrc1 + (KC), _d + 1024);                 \
    } while (0)
#define STAGE_B(P, KC)                                    \
    do {                                                  \
        char* _d = smem + 49152 + (P) * 8192 + w * 1024;  \
        gload16(bSrc + (KC), _d);                         \
    } while (0)

    i32x4 acc[4][4] = {};
    i32x4 a[4], b[4];

    // prologue: stage tiles 0,1,2 (9 loads); drain tile 0, keep 6 in flight
    STAGE_A(0, 0);
    STAGE_B(0, 0);
    STAGE_A(1, 64);
    STAGE_B(1, 64);
    STAGE_A(2, 128);
    STAGE_B(2, 128);
    asm volatile("s_waitcnt vmcnt(6)" ::: "memory");
    __builtin_amdgcn_s_barrier();

    for (int t = 0; t < NT; ++t) {
        // dual-i8 fold: scale part1's exact integer sum by 255 before part2
        if (t == fold_t) {
#pragma unroll
            for (int mi = 0; mi < 4; ++mi)
#pragma unroll
                for (int ni = 0; ni < 4; ++ni)
                    acc[mi][ni] *= 255;
        }
        const int p = t % 3;
        const char* Ab = smem + p * 16384;
        const char* Bb = smem + 49152 + p * 8192;

        // ---- all 8 fragment reads upfront; MFMA cluster (lgkm staggered) ----
        a[0] = *(const i32x4*)(Ab + rdA);
#pragma unroll
        for (int n = 0; n < 4; ++n) b[n] = *(const i32x4*)(Bb + rdB + n * 1024);
#pragma unroll
        for (int f = 1; f < 4; ++f) a[f] = *(const i32x4*)(Ab + rdA + f * 1024);

        __builtin_amdgcn_s_setprio(1);
#pragma unroll
        for (int f = 0; f < 4; ++f)
#pragma unroll
            for (int n = 0; n < 4; ++n)
                acc[f][n] = MFMA_I8(a[f], b[n], acc[f][n]);
        __builtin_amdgcn_s_setprio(0);

        // rule #18: pin the read-drain before the barrier
        asm volatile("s_waitcnt lgkmcnt(0)" ::: "memory");
        __builtin_amdgcn_sched_barrier(0);
        // bar1: every wave's reads of buf[p] complete -> safe to overwrite
        __builtin_amdgcn_s_barrier();

        // stage tile t+3 into the just-freed buffer p
        if (t + 3 < NT) {
            const int kc = (t + 3) << 6;
            const int bc = (kc >= bwrap) ? kc - bwrap : kc;
            STAGE_B(p, bc);
            STAGE_A(p, kc);
            asm volatile("s_waitcnt vmcnt(6)" ::: "memory");  // drain t+1 only
        } else if (t + 2 < NT) {
            asm volatile("s_waitcnt vmcnt(3)" ::: "memory");
        } else {
            asm volatile("s_waitcnt vmcnt(0)" ::: "memory");
        }
        // bar2: tile t+1's LDS is ready block-wide
        __builtin_amdgcn_s_barrier();
    }

    // ---- epilogue ----
    const float s1 = __uint_as_float(slots[EPI]) / 127.0f;
    const int mbase = m0 + wm + lkg * 4;
    const int nbase = n0 + wn + lr16;
    if constexpr (EPI == 0) {
        const float sx = __uint_as_float(slots[2]) / 127.0f;
        const float c1s = sx * s1 * (1.0f / 255.0f);
        const float inv_sg = 1.0f / *sg_ptr;
#pragma unroll
        for (int mi = 0; mi < 4; ++mi)
#pragma unroll
            for (int ni = 0; ni < 4; ++ni) {
                const int n = nbase + ni * 16;
                const float bn = bias[n];
#pragma unroll
                for (int e = 0; e < 4; ++e) {
                    const int m = mbase + mi * 16 + e;
                    float h = (float)acc[mi][ni][e] * c1s + bn;
                    float g = 0.5f * h * (1.0f + erff(h * 0.70710678118654752f));
                    float q = fminf(fmaxf(rintf(g * inv_sg), -128.f), 127.f);
                    out_b[(size_t)m * N + n] = (signed char)(int)q;
                }
            }
    } else {
        const float sg = *sg_ptr;
        const float so = *so_ptr;
        const float inv_so = 1.0f / so;
        const float c2s = sg * s1;
#pragma unroll
        for (int mi = 0; mi < 4; ++mi)
#pragma unroll
            for (int ni = 0; ni < 4; ++ni) {
                const int n = nbase + ni * 16;
                const float bn = bias[n];
#pragma unroll
                for (int e = 0; e < 4; ++e) {
                    const int m = mbase + mi * 16 + e;
                    float y = (float)acc[mi][ni][e] * c2s + bn;
                    float q = fminf(fmaxf(rintf(y * inv_so), -128.f), 127.f);
                    out_f[(size_t)m * N + n] = q * so;
                }
            }
    }
#undef STAGE_A
#undef STAGE_B
}

extern "C" void kernel_launch(void* const* d_in, const int* in_sizes, int n_in,
                              void* d_out, int out_size, void* d_ws, size_t ws_size,
                              hipStream_t stream) {
    const float* x  = (const float*)d_in[0];
    const float* W1 = (const float*)d_in[1];
    const float* b1 = (const float*)d_in[2];
    const float* W2 = (const float*)d_in[3];
    const float* b2 = (const float*)d_in[4];
    const float* sg = (const float*)d_in[5];
    const float* so = (const float*)d_in[6];

    const int M = 64 * 196;  // 12544
    const int D = 768;
    const int H = 3072;

    char* ws = (char*)d_ws;
    unsigned* slots = (unsigned*)ws;                 // [0]=|W1| [1]=|W2| [2]=|x|
    signed char* xq    = (signed char*)(ws + 256);   // M x 1536 (q1|q2)
    signed char* w1int = xq + (size_t)M * 1536;      // H x D
    signed char* w2int = w1int + (size_t)H * D;      // D x H
    signed char* qact  = w2int + (size_t)D * H;      // M x H

    hipFuncSetAttribute(reinterpret_cast<const void*>(gemm_i8<0>),
                        hipFuncAttributeMaxDynamicSharedMemorySize, 73728);
    hipFuncSetAttribute(reinterpret_cast<const void*>(gemm_i8<1>),
                        hipFuncAttributeMaxDynamicSharedMemorySize, 73728);

    init_slots<<<1, 64, 0, stream>>>(slots);
    const int n4w = (H * D) / 4;
    const int n4x = (M * D) / 4;
    absmax3_kernel<<<dim3(512, 3), 256, 0, stream>>>(W1, W2, x, n4w, n4x, slots);
    prep_kernel<<<dim3(1024, 3), 256, 0, stream>>>(W1, w1int, W2, w2int, x, xq,
                                                   n4w, n4x, slots);

    // GEMM1: A=xq [M][1536] (q1|q2), B=w1int [H][768]; NT=24, fold t=12, B wraps 768
    dim3 g1(M / 256, H / 128);  // 49 x 24 = 1176 blocks
    gemm_i8<0><<<g1, 512, 73728, stream>>>(
        xq, w1int, b1, slots, sg, so, qact, nullptr, H, 1536, D, 24, D, 12);

    // GEMM2: A=qact [M][3072], B=w2int [D][3072]; NT=48, no fold, no wrap
    dim3 g2(M / 256, D / 128);  // 49 x 6 = 294 blocks
    gemm_i8<1><<<g2, 512, 73728, stream>>>(
        qact, w2int, b2, slots, sg, so, nullptr, (float*)d_out, D, 3072, H, 48, 1 << 30, -1);
}

// Round 13
// 239.471 us; speedup vs baseline: 1.0802x; 1.0802x over previous
//
#include <hip/hip_runtime.h>
#include <math.h>

typedef __attribute__((ext_vector_type(4))) int i32x4;

#define MFMA_I8(a, b, c) __builtin_amdgcn_mfma_i32_16x16x64_i8((a), (b), (c), 0, 0, 0)

__device__ __forceinline__ void gload16(const void* g, void* l) {
    __builtin_amdgcn_global_load_lds(
        (const __attribute__((address_space(1))) unsigned int*)g,
        (__attribute__((address_space(3))) unsigned int*)l, 16, 0, 0);
}

// ---------- prologue ----------
__global__ void init_slots(unsigned* slots) {
    if (threadIdx.x < 3) slots[threadIdx.x] = 0u;
}

// blockIdx.y: 0 -> W1, 1 -> W2, 2 -> x
__global__ void absmax3_kernel(const float* __restrict__ W1, const float* __restrict__ W2,
                               const float* __restrict__ x, int n4w, int n4x,
                               unsigned* __restrict__ slots) {
    const float* p = (blockIdx.y == 0) ? W1 : (blockIdx.y == 1) ? W2 : x;
    const int n4 = (blockIdx.y == 2) ? n4x : n4w;
    float m = 0.f;
    const float4* p4 = (const float4*)p;
    for (int i = blockIdx.x * blockDim.x + threadIdx.x; i < n4; i += gridDim.x * blockDim.x) {
        float4 v = p4[i];
        m = fmaxf(m, fmaxf(fmaxf(fabsf(v.x), fabsf(v.y)), fmaxf(fabsf(v.z), fabsf(v.w))));
    }
#pragma unroll
    for (int off = 32; off > 0; off >>= 1)
        m = fmaxf(m, __shfl_xor(m, off, 64));
    if ((threadIdx.x & 63) == 0) atomicMax(slots + blockIdx.y, __float_as_uint(m));
}

__device__ __forceinline__ int pack4(float a, float b, float c, float d) {
    return (int)(((unsigned)(unsigned char)(signed char)(int)a) |
                 (((unsigned)(unsigned char)(signed char)(int)b) << 8) |
                 (((unsigned)(unsigned char)(signed char)(int)c) << 16) |
                 (((unsigned)(unsigned char)(signed char)(int)d) << 24));
}

// blockIdx.y: 0 -> quant W1 -> i8, 1 -> quant W2 -> i8, 2 -> split x -> (q1|q2) i8
__global__ void prep_kernel(const float* __restrict__ W1, signed char* __restrict__ o1,
                            const float* __restrict__ W2, signed char* __restrict__ o2,
                            const float* __restrict__ x, signed char* __restrict__ xq,
                            int n4w, int n4x, const unsigned* __restrict__ slots) {
    if (blockIdx.y < 2) {
        const float* W = blockIdx.y ? W2 : W1;
        signed char* out = blockIdx.y ? o2 : o1;
        const float inv_s = 127.0f / __uint_as_float(slots[blockIdx.y]);
        const float4* W4 = (const float4*)W;
        for (int i = blockIdx.x * blockDim.x + threadIdx.x; i < n4w; i += gridDim.x * blockDim.x) {
            float4 v = W4[i];
            float q0 = fminf(fmaxf(rintf(v.x * inv_s), -127.f), 127.f);
            float q1 = fminf(fmaxf(rintf(v.y * inv_s), -127.f), 127.f);
            float q2 = fminf(fmaxf(rintf(v.z * inv_s), -127.f), 127.f);
            float q3 = fminf(fmaxf(rintf(v.w * inv_s), -127.f), 127.f);
            *(int*)(out + 4 * (size_t)i) = pack4(q0, q1, q2, q3);
        }
    } else {
        const float sx = __uint_as_float(slots[2]) / 127.0f;
        const float inv_sx = 1.0f / sx;
        const float r_scale = 255.0f * inv_sx;
        const float4* x4 = (const float4*)x;
        for (int i = blockIdx.x * blockDim.x + threadIdx.x; i < n4x; i += gridDim.x * blockDim.x) {
            int r = i / 192;  // 192 float4 per 768-row
            int c = (i - r * 192) * 4;
            float4 v = x4[i];
            float a0 = rintf(v.x * inv_sx), a1 = rintf(v.y * inv_sx);
            float a2 = rintf(v.z * inv_sx), a3 = rintf(v.w * inv_sx);
            float b0 = fminf(fmaxf(rintf((v.x - sx * a0) * r_scale), -127.f), 127.f);
            float b1 = fminf(fmaxf(rintf((v.y - sx * a1) * r_scale), -127.f), 127.f);
            float b2 = fminf(fmaxf(rintf((v.z - sx * a2) * r_scale), -127.f), 127.f);
            float b3 = fminf(fmaxf(rintf((v.w - sx * a3) * r_scale), -127.f), 127.f);
            size_t base = (size_t)r * 1536 + c;
            *(int*)(xq + base) = pack4(a0, a1, a2, a3);
            *(int*)(xq + base + 768) = pack4(b0, b1, b2, b3);
        }
    }
}

// ---------- 256x128 i8 GEMM (NT): acc = sum_k A[m,k]*B[n,(k mod bwrap)] ----------
// BK=64, 8 waves 4m x 2n (wave tile 64x64), LDS 48KB dbuf, packed 2-rows-per-128B-line
// granule-XOR swizzle (conflict-free, R10-verified), reads-upfront 2-barrier tile (R11).
// NEW (R13): tile-mapping axis flipped — within each XCD's contiguous wg range the
// N-index runs FASTEST, so the gY blocks sharing one 256-row A-panel are co-resident
// on one XCD and the panel stays L2-resident (R12 post-mortem: m-fastest mapping
// blew the 4MB L2 -> 215MB HBM fetch = 5x over-fetch; time tracked fetch linearly).
template <int EPI>
__global__ __launch_bounds__(512, 4) void gemm_i8(
    const signed char* __restrict__ A, const signed char* __restrict__ B,
    const float* __restrict__ bias, const unsigned* __restrict__ slots,
    const float* __restrict__ sg_ptr, const float* __restrict__ so_ptr,
    signed char* __restrict__ out_b, float* __restrict__ out_f,
    int N, int lda, int ldb, int NT, int bwrap, int fold_t) {
    extern __shared__ char smem[];  // A: [2][16KB] @0, B: [2][8KB] @32768

    const int tid = threadIdx.x;
    const int lane = tid & 63;
    const int w = tid >> 6;
    const int wm = (w >> 1) * 64;  // 4m x 2n wave grid
    const int wn = (w & 1) * 64;
    const int lr16 = lane & 15;
    const int lkg = lane >> 4;

    // bijective XCD-aware swizzle (m204): XCD x owns a contiguous wg range
    const int gX = gridDim.x;
    const int gY = gridDim.y;  // number of n-blocks (A-panel sharers)
    const int nwg = gX * gY;
    const int orig = blockIdx.y * gX + blockIdx.x;
    const int qq = nwg >> 3, rr = nwg & 7;
    const int xcd = orig & 7, idx = orig >> 3;
    const int wg = (xcd < rr ? xcd * (qq + 1) : rr * (qq + 1) + (xcd - rr) * qq) + idx;
    // R13: n fastest -> same-XCD neighbors share the 256-row A-panel (L2-resident)
    const int m0 = (wg / gY) * 256;
    const int n0 = (wg % gY) * 128;

    // read-side: packed layout. global(row R, k-granule q) lives at
    // LDS line L=R>>1, phys granule p = ((R&1)*4+q) ^ (L&7). Here L&7 == lr16>>1.
    const int h8 = lr16 >> 1;
    const int pG = (((lr16 & 1) << 2) + lkg) ^ h8;
    const int rdA = wm * 64 + h8 * 128 + pG * 16;           // + f*1024 + buf*16384
    const int rdB = 32768 + wn * 64 + h8 * 128 + pG * 16;   // + n*1024 + buf*8192

    // stage-side: linear LDS dest (DMA), inverse-swizzled global source.
    const int Lw = lane >> 3;
    const int ll = (lane & 7) ^ Lw;
    const int dr = ll >> 2;
    const int dk = (ll & 3) << 4;
    const signed char* aSrc0 = A + (size_t)(m0 + w * 32 + 2 * Lw + dr) * lda + dk;
    const signed char* aSrc1 = A + (size_t)(m0 + w * 32 + 16 + 2 * Lw + dr) * lda + dk;
    const signed char* bSrc  = B + (size_t)(n0 + w * 16 + 2 * Lw + dr) * ldb + dk;

#define STAGE_A(P, KC)                                  \
    do {                                                \
        char* _d = smem + ((P) << 14) + w * 2048;       \
        gload16(aSrc0 + (KC), _d);                      \
        gload16(aSrc1 + (KC), _d + 1024);               \
    } while (0)
#define STAGE_B(P, KC)                                  \
    do {                                                \
        char* _d = smem + 32768 + ((P) << 13) + w * 1024; \
        gload16(bSrc + (KC), _d);                       \
    } while (0)

    i32x4 acc[4][4] = {};
    i32x4 a[4], b[4];

    // prologue: stage tiles 0,1 (3 loads each); drain tile 0, keep tile 1 in flight
    STAGE_A(0, 0);
    STAGE_B(0, 0);
    STAGE_A(1, 64);
    STAGE_B(1, 64);
    asm volatile("s_waitcnt vmcnt(3)" ::: "memory");
    __builtin_amdgcn_s_barrier();

    for (int t = 0; t < NT; ++t) {
        // dual-i8 fold: scale part1's exact integer sum by 255 before part2
        if (t == fold_t) {
#pragma unroll
            for (int mi = 0; mi < 4; ++mi)
#pragma unroll
                for (int ni = 0; ni < 4; ++ni)
                    acc[mi][ni] *= 255;
        }
        const int p = t & 1;
        const char* Ab = smem + (p << 14);
        const char* Bb = smem + (p << 13);  // rdB carries the +32768
        const bool pre = (t + 2) < NT;
        const int kc = (t + 2) << 6;
        const int bc = (kc >= bwrap) ? kc - bwrap : kc;

        // ---- all 8 fragment reads upfront (read latency overlaps MFMA cluster) ----
        a[0] = *(const i32x4*)(Ab + rdA);
#pragma unroll
        for (int n = 0; n < 4; ++n) b[n] = *(const i32x4*)(Bb + rdB + n * 1024);
#pragma unroll
        for (int f = 1; f < 4; ++f) a[f] = *(const i32x4*)(Ab + rdA + f * 1024);

        // ---- 16 MFMA; compiler staggers lgkmcnt waits across the cluster ----
        __builtin_amdgcn_s_setprio(1);
#pragma unroll
        for (int f = 0; f < 4; ++f)
#pragma unroll
            for (int n = 0; n < 4; ++n)
                acc[f][n] = MFMA_I8(a[f], b[n], acc[f][n]);
        __builtin_amdgcn_s_setprio(0);

        // rule #18: pin the read-drain before the barrier
        asm volatile("s_waitcnt lgkmcnt(0)" ::: "memory");
        __builtin_amdgcn_sched_barrier(0);
        // bar1: every wave's reads of buf[p] complete -> safe to overwrite
        __builtin_amdgcn_s_barrier();

        if (pre) {
            STAGE_B(p, bc);
            STAGE_A(p, kc);
            asm volatile("s_waitcnt vmcnt(3)" ::: "memory");  // drain t+1, keep t+2
        } else {
            asm volatile("s_waitcnt vmcnt(0)" ::: "memory");  // tail: drain everything
        }
        // bar2: tile t+1's LDS is ready block-wide
        __builtin_amdgcn_s_barrier();
    }

    // ---- epilogue ----
    const float s1 = __uint_as_float(slots[EPI]) / 127.0f;
    const int mbase = m0 + wm + lkg * 4;
    const int nbase = n0 + wn + lr16;
    if constexpr (EPI == 0) {
        const float sx = __uint_as_float(slots[2]) / 127.0f;
        const float c1s = sx * s1 * (1.0f / 255.0f);
        const float inv_sg = 1.0f / *sg_ptr;
#pragma unroll
        for (int mi = 0; mi < 4; ++mi)
#pragma unroll
            for (int ni = 0; ni < 4; ++ni) {
                const int n = nbase + ni * 16;
                const float bn = bias[n];
#pragma unroll
                for (int e = 0; e < 4; ++e) {
                    const int m = mbase + mi * 16 + e;
                    float h = (float)acc[mi][ni][e] * c1s + bn;
                    float g = 0.5f * h * (1.0f + erff(h * 0.70710678118654752f));
                    float q = fminf(fmaxf(rintf(g * inv_sg), -128.f), 127.f);
                    out_b[(size_t)m * N + n] = (signed char)(int)q;
                }
            }
    } else {
        const float sg = *sg_ptr;
        const float so = *so_ptr;
        const float inv_so = 1.0f / so;
        const float c2s = sg * s1;
#pragma unroll
        for (int mi = 0; mi < 4; ++mi)
#pragma unroll
            for (int ni = 0; ni < 4; ++ni) {
                const int n = nbase + ni * 16;
                const float bn = bias[n];
#pragma unroll
                for (int e = 0; e < 4; ++e) {
                    const int m = mbase + mi * 16 + e;
                    float y = (float)acc[mi][ni][e] * c2s + bn;
                    float q = fminf(fmaxf(rintf(y * inv_so), -128.f), 127.f);
                    out_f[(size_t)m * N + n] = q * so;
                }
            }
    }
#undef STAGE_A
#undef STAGE_B
}

extern "C" void kernel_launch(void* const* d_in, const int* in_sizes, int n_in,
                              void* d_out, int out_size, void* d_ws, size_t ws_size,
                              hipStream_t stream) {
    const float* x  = (const float*)d_in[0];
    const float* W1 = (const float*)d_in[1];
    const float* b1 = (const float*)d_in[2];
    const float* W2 = (const float*)d_in[3];
    const float* b2 = (const float*)d_in[4];
    const float* sg = (const float*)d_in[5];
    const float* so = (const float*)d_in[6];

    const int M = 64 * 196;  // 12544
    const int D = 768;
    const int H = 3072;

    char* ws = (char*)d_ws;
    unsigned* slots = (unsigned*)ws;                 // [0]=|W1| [1]=|W2| [2]=|x|
    signed char* xq    = (signed char*)(ws + 256);   // M x 1536 (q1|q2)
    signed char* w1int = xq + (size_t)M * 1536;      // H x D
    signed char* w2int = w1int + (size_t)H * D;      // D x H
    signed char* qact  = w2int + (size_t)D * H;      // M x H

    hipFuncSetAttribute(reinterpret_cast<const void*>(gemm_i8<0>),
                        hipFuncAttributeMaxDynamicSharedMemorySize, 49152);
    hipFuncSetAttribute(reinterpret_cast<const void*>(gemm_i8<1>),
                        hipFuncAttributeMaxDynamicSharedMemorySize, 49152);

    init_slots<<<1, 64, 0, stream>>>(slots);
    const int n4w = (H * D) / 4;
    const int n4x = (M * D) / 4;
    absmax3_kernel<<<dim3(512, 3), 256, 0, stream>>>(W1, W2, x, n4w, n4x, slots);
    prep_kernel<<<dim3(1024, 3), 256, 0, stream>>>(W1, w1int, W2, w2int, x, xq,
                                                   n4w, n4x, slots);

    // GEMM1: A=xq [M][1536] (q1|q2), B=w1int [H][768]; NT=24, fold t=12, B wraps 768
    dim3 g1(M / 256, H / 128);  // 49 x 24 = 1176 blocks
    gemm_i8<0><<<g1, 512, 49152, stream>>>(
        xq, w1int, b1, slots, sg, so, qact, nullptr, H, 1536, D, 24, D, 12);

    // GEMM2: A=qact [M][3072], B=w2int [D][3072]; NT=48, no fold, no wrap
    dim3 g2(M / 256, D / 128);  // 49 x 6 = 294 blocks
    gemm_i8<1><<<g2, 512, 49152, stream>>>(
        qact, w2int, b2, slots, sg, so, nullptr, (float*)d_out, D, 3072, H, 48, 1 << 30, -1);
}